// Round 1
// baseline (259.284 us; speedup 1.0000x reference)
//
#include <hip/hip_runtime.h>
#include <math.h>

// BundleAdjustmentModel: project N 3D points into V=64 camera views.
// out[v][n] = (u,v) with u = -f*X/safe_z + cx, v = f*Y/safe_z + cy,
// [X,Y,Z] = R_v * p_n + t_v,  R_v = Rx*Ry*Rz (euler xyz), t_v = (tx,ty,-(softplus(d)+0.25))
//
// Memory-bound: writes 256 MB, reads 6 MB. Each thread holds PPT points in
// registers and loops over all 64 views; per-view constants live in LDS
// (broadcast reads, conflict-free). Stores are coalesced float2.

#define NVIEW 64
#define BLOCK 256
#define PPT 2            // points per thread: amortizes the 3 ds_read_b128/view
#define Z_EPS 1e-4f

__device__ __forceinline__ float softplus_f(float x) {
    // stable: max(x,0) + log1p(exp(-|x|))
    return fmaxf(x, 0.0f) + log1pf(expf(-fabsf(x)));
}

__global__ __launch_bounds__(BLOCK) void ba_project_kernel(
    const float* __restrict__ points,          // (N,3)
    const float* __restrict__ euler,           // (V,3)
    const float* __restrict__ txy,             // (V,2)
    const float* __restrict__ tdr,             // (V,)
    const float* __restrict__ focal_raw,       // (1,)
    const int*   __restrict__ cxp,             // (1,)
    const int*   __restrict__ cyp,             // (1,)
    float2* __restrict__ out,                  // (V,N) float2
    int N)
{
    // Per-view constants: rows of [R | t] packed as 3 float4s per view.
    __shared__ float4 vd[NVIEW * 3];

    const int tid = threadIdx.x;

    if (tid < NVIEW) {
        float ex = euler[tid * 3 + 0];
        float ey = euler[tid * 3 + 1];
        float ez = euler[tid * 3 + 2];
        float sx, cx_, sy, cy_, sz, cz;
        sincosf(ex, &sx, &cx_);
        sincosf(ey, &sy, &cy_);
        sincosf(ez, &sz, &cz);
        // R = Rx @ Ry @ Rz
        float r00 = cy_ * cz;
        float r01 = -cy_ * sz;
        float r02 = sy;
        float r10 = cx_ * sz + sx * sy * cz;
        float r11 = cx_ * cz - sx * sy * sz;
        float r12 = -sx * cy_;
        float r20 = sx * sz - cx_ * sy * cz;
        float r21 = sx * cz + cx_ * sy * sz;
        float r22 = cx_ * cy_;

        float tx = txy[tid * 2 + 0];
        float ty = txy[tid * 2 + 1];
        float tz = -(softplus_f(tdr[tid]) + 0.25f);

        vd[tid * 3 + 0] = make_float4(r00, r01, r02, tx);
        vd[tid * 3 + 1] = make_float4(r10, r11, r12, ty);
        vd[tid * 3 + 2] = make_float4(r20, r21, r22, tz);
    }
    __syncthreads();

    const float focal = softplus_f(focal_raw[0]) + 50.0f;
    const float ccx = (float)cxp[0];
    const float ccy = (float)cyp[0];

    const int base = blockIdx.x * (BLOCK * PPT) + tid;

    float px[PPT], py[PPT], pz[PPT];
    int   n[PPT];
    bool  ok[PPT];
#pragma unroll
    for (int k = 0; k < PPT; ++k) {
        n[k]  = base + k * BLOCK;
        ok[k] = n[k] < N;
        int i = ok[k] ? n[k] * 3 : 0;   // clamp OOB lanes to a safe address
        px[k] = points[i + 0];
        py[k] = points[i + 1];
        pz[k] = points[i + 2];
    }

    for (int v = 0; v < NVIEW; ++v) {
        float4 ra = vd[v * 3 + 0];   // broadcast ds_read_b128, conflict-free
        float4 rb = vd[v * 3 + 1];
        float4 rc = vd[v * 3 + 2];
#pragma unroll
        for (int k = 0; k < PPT; ++k) {
            float X = fmaf(ra.x, px[k], fmaf(ra.y, py[k], fmaf(ra.z, pz[k], ra.w)));
            float Y = fmaf(rb.x, px[k], fmaf(rb.y, py[k], fmaf(rb.z, pz[k], rb.w)));
            float Z = fmaf(rc.x, px[k], fmaf(rc.y, py[k], fmaf(rc.z, pz[k], rc.w)));

            // safe_z = sign(z) * max(|z|, eps), with sign(z>=0)=+1 (matches ref)
            float sgn  = (Z >= 0.0f) ? 1.0f : -1.0f;
            float safe = sgn * fmaxf(fabsf(Z), Z_EPS);

            // 1-ulp hardware reciprocal; error ~1e-7 rel, threshold is ~2% rel.
            float t = focal * __builtin_amdgcn_rcpf(safe);

            float u = fmaf(-X, t, ccx);
            float w = fmaf( Y, t, ccy);

            if (ok[k]) out[(size_t)v * N + n[k]] = make_float2(u, w);
        }
    }
}

extern "C" void kernel_launch(void* const* d_in, const int* in_sizes, int n_in,
                              void* d_out, int out_size, void* d_ws, size_t ws_size,
                              hipStream_t stream) {
    const float* points    = (const float*)d_in[0];
    const float* euler     = (const float*)d_in[1];
    const float* txy       = (const float*)d_in[2];
    const float* tdr       = (const float*)d_in[3];
    const float* focal_raw = (const float*)d_in[4];
    const int*   cxp       = (const int*)d_in[5];
    const int*   cyp       = (const int*)d_in[6];

    const int N = in_sizes[0] / 3;
    const int blocks = (N + BLOCK * PPT - 1) / (BLOCK * PPT);

    ba_project_kernel<<<blocks, BLOCK, 0, stream>>>(
        points, euler, txy, tdr, focal_raw, cxp, cyp, (float2*)d_out, N);
}